// Round 1
// baseline (702.627 us; speedup 1.0000x reference)
//
#include <hip/hip_runtime.h>
#include <math.h>

#define BM 64
#define BK 32
#define NLAT 256
#define NNOD 256

typedef float f4 __attribute__((ext_vector_type(4)));

__device__ __forceinline__ void gload_lds16(const void* g, void* l) {
  __builtin_amdgcn_global_load_lds((const __attribute__((address_space(1))) void*)g,
                                   (__attribute__((address_space(3))) void*)l, 16, 0, 0);
}

// prep: Et[k][n] = E[n][k];  e2[n] = sum_k E[n][k]^2
__global__ void prep_kernel(const float* __restrict__ E, float* __restrict__ Et,
                            float* __restrict__ e2) {
  const int n = blockIdx.x;
  const int k = threadIdx.x;
  float v = E[n * NLAT + k];
  Et[k * NNOD + n] = v;
  float s = v * v;
#pragma unroll
  for (int m = 1; m <= 32; m <<= 1) s += __shfl_xor(s, m);
  __shared__ float ws[4];
  if ((threadIdx.x & 63) == 0) ws[threadIdx.x >> 6] = s;
  __syncthreads();
  if (threadIdx.x == 0) e2[n] = ws[0] + ws[1] + ws[2] + ws[3];
}

__launch_bounds__(256, 3)
__global__ void som_kernel(const float* __restrict__ Z, const float* __restrict__ E,
                           const float* __restrict__ Et, const float* __restrict__ e2g,
                           const int* __restrict__ alphap,
                           float* __restrict__ out_zq, float* __restrict__ out_nbr,
                           float* __restrict__ out_q, float* __restrict__ out_bmu) {
  __shared__ float As[BM][BK];    // 8 KB, row-major (same layout as Z slice)
  __shared__ float Bs[BK][NNOD];  // 32 KB, Bs[k][n] = Et[k0+k][n]
  __shared__ float z2s[BM];

  const int tid = threadIdx.x;
  const int lane = tid & 63;
  const int wv = tid >> 6;  // wave 0..3
  const int tr = tid >> 5;  // row group 0..7  (8 rows each)
  const int tc = tid & 31;  // col group 0..31 (8 cols each)
  const long brow = (long)blockIdx.x * BM;

  float acc[8][8];
#pragma unroll
  for (int i = 0; i < 8; ++i)
#pragma unroll
    for (int j = 0; j < 8; ++j) acc[i][j] = 0.f;

  float z2p = 0.f;
  const int m2 = tid >> 2;  // 0..63 : row whose ||z||^2 partial this thread owns
  const int kq = tid & 3;

#pragma unroll 1
  for (int ks = 0; ks < 8; ++ks) {
    const int k0 = ks * BK;
    __syncthreads();
    // stage A tile (64x32 f32 = 8KB) : 8 x 1KB global_load_lds, 2 per wave
#pragma unroll
    for (int t = 0; t < 2; ++t) {
      const int q = wv * 2 + t;
      const int m = q * 8 + (lane >> 3);
      const float* src = Z + (brow + m) * NLAT + k0 + (lane & 7) * 4;
      gload_lds16(src, &As[q * 8][0]);
    }
    // stage B tile (32x256 f32 = 32KB) : 32 x 1KB rows of Et, 8 per wave
#pragma unroll
    for (int t = 0; t < 8; ++t) {
      const int kk = wv * 8 + t;
      const float* src = Et + (long)(k0 + kk) * NNOD + lane * 4;
      gload_lds16(src, &Bs[kk][0]);
    }
    __syncthreads();
    // ||z||^2 partial from staged A tile (cheap: 8 FMA/thread/step)
    {
      f4 s0 = *(const f4*)&As[m2][kq * 8];
      f4 s1 = *(const f4*)&As[m2][kq * 8 + 4];
      z2p += s0[0] * s0[0] + s0[1] * s0[1] + s0[2] * s0[2] + s0[3] * s0[3] +
             s1[0] * s1[0] + s1[1] * s1[1] + s1[2] * s1[2] + s1[3] * s1[3];
    }
    // GEMM: 8x8 register tile, a-reads broadcast across tc, b-reads 2x b128
#pragma unroll
    for (int kb = 0; kb < 8; ++kb) {
      f4 av[8];
#pragma unroll
      for (int i = 0; i < 8; ++i) av[i] = *(const f4*)&As[tr * 8 + i][kb * 4];
#pragma unroll
      for (int kk = 0; kk < 4; ++kk) {
        f4 b0 = *(const f4*)&Bs[kb * 4 + kk][tc * 8];
        f4 b1 = *(const f4*)&Bs[kb * 4 + kk][tc * 8 + 4];
#pragma unroll
        for (int i = 0; i < 8; ++i) {
          const float a = av[i][kk];
          acc[i][0] = fmaf(a, b0[0], acc[i][0]);
          acc[i][1] = fmaf(a, b0[1], acc[i][1]);
          acc[i][2] = fmaf(a, b0[2], acc[i][2]);
          acc[i][3] = fmaf(a, b0[3], acc[i][3]);
          acc[i][4] = fmaf(a, b1[0], acc[i][4]);
          acc[i][5] = fmaf(a, b1[1], acc[i][5]);
          acc[i][6] = fmaf(a, b1[2], acc[i][6]);
          acc[i][7] = fmaf(a, b1[3], acc[i][7]);
        }
      }
    }
  }

  // finish ||z||^2 : reduce over the 4 kq lanes, publish to LDS
  z2p += __shfl_xor(z2p, 1);
  z2p += __shfl_xor(z2p, 2);
  if (kq == 0) z2s[m2] = z2p;
  __syncthreads();

  const float alpha = (float)(*alphap);
  const float ex = (alpha + 1.f) * 0.5f;
  const float ra = 1.f / alpha;
  f4 e2a = *(const f4*)&e2g[tc * 8];
  f4 e2b = *(const f4*)&e2g[tc * 8 + 4];
  float e2r[8] = {e2a[0], e2a[1], e2a[2], e2a[3], e2b[0], e2b[1], e2b[2], e2b[3]};

#pragma unroll 1
  for (int i = 0; i < 8; ++i) {
    const int rloc = tr * 8 + i;
    const long row = brow + rloc;
    const float z2 = z2s[rloc];
    float d[8];
#pragma unroll
    for (int j = 0; j < 8; ++j)
      d[j] = fmaxf(z2 + e2r[j] - 2.f * acc[i][j], 0.f);
    // argmin over this row (first-index tie-break, matching numpy)
    float dm = d[0];
    int im = tc * 8;
#pragma unroll
    for (int j = 1; j < 8; ++j) {
      if (d[j] < dm) { dm = d[j]; im = tc * 8 + j; }
    }
#pragma unroll
    for (int m = 1; m <= 16; m <<= 1) {
      float od = __shfl_xor(dm, m);
      int oi = __shfl_xor(im, m);
      if (od < dm || (od == dm && oi < im)) { dm = od; im = oi; }
    }
    // q = (1/(1+d/a))^((a+1)/2), row-normalized, + eps
    float qv[8];
    float qs = 0.f;
#pragma unroll
    for (int j = 0; j < 8; ++j) {
      float u = 1.f / (1.f + d[j] * ra);
      qv[j] = __expf(ex * __logf(u));
      qs += qv[j];
    }
#pragma unroll
    for (int m = 1; m <= 16; m <<= 1) qs += __shfl_xor(qs, m);
    const float ri = 1.f / qs;
    f4 q0, q1;
#pragma unroll
    for (int j = 0; j < 4; ++j) {
      q0[j] = qv[j] * ri + 1.1920929e-7f;
      q1[j] = qv[j + 4] * ri + 1.1920929e-7f;
    }
    *(f4*)&out_q[row * NNOD + tc * 8] = q0;
    *(f4*)&out_q[row * NNOD + tc * 8 + 4] = q1;

    const int bmu = im;
    if (tc == 0) out_bmu[row] = (float)bmu;

    const int k1 = bmu >> 4, k2 = bmu & 15;
    int nidx[5];
    nidx[0] = bmu;                              // self
    nidx[1] = ((k1 + 15) & 15) * 16 + k2;       // up
    nidx[2] = ((k1 + 1) & 15) * 16 + k2;        // down
    nidx[3] = (k1 << 4) + ((k2 + 1) & 15);      // right
    nidx[4] = (k1 << 4) + ((k2 + 15) & 15);     // left
#pragma unroll
    for (int nb = 0; nb < 5; ++nb) {
      f4 v0 = *(const f4*)&E[nidx[nb] * NLAT + tc * 8];  // L2-hot gather
      f4 v1 = *(const f4*)&E[nidx[nb] * NLAT + tc * 8 + 4];
      *(f4*)&out_nbr[(row * 5 + nb) * NLAT + tc * 8] = v0;
      *(f4*)&out_nbr[(row * 5 + nb) * NLAT + tc * 8 + 4] = v1;
      if (nb == 0) {
        *(f4*)&out_zq[row * NLAT + tc * 8] = v0;
        *(f4*)&out_zq[row * NLAT + tc * 8 + 4] = v1;
      }
    }
  }
}

extern "C" void kernel_launch(void* const* d_in, const int* in_sizes, int n_in,
                              void* d_out, int out_size, void* d_ws, size_t ws_size,
                              hipStream_t stream) {
  const float* Z = (const float*)d_in[0];
  const float* E = (const float*)d_in[1];
  const int* alphap = (const int*)d_in[2];
  const long N = (long)in_sizes[0] / NLAT;  // 65536

  float* Et = (float*)d_ws;                              // 256*256*4 = 262144 B
  float* e2 = (float*)((char*)d_ws + NLAT * NNOD * 4);   // 1 KB

  float* out = (float*)d_out;
  float* out_zq = out;                          // [N,256]
  float* out_nbr = out + N * NLAT;              // [N,5,256]
  float* out_q = out + N * NLAT + N * 5 * NLAT; // [N,256]
  float* out_bmu = out + N * NLAT * 2 + N * 5 * NLAT;  // [N] as float

  prep_kernel<<<NNOD, 256, 0, stream>>>(E, Et, e2);
  som_kernel<<<(int)(N / BM), 256, 0, stream>>>(Z, E, Et, e2, alphap,
                                                out_zq, out_nbr, out_q, out_bmu);
}